// Round 7
// baseline (8282.938 us; speedup 1.0000x reference)
//
#include <hip/hip_runtime.h>
#include <hip/hip_bf16.h>
#include <stdint.h>

#define SEQ 2048
#define IN_DIM 2048
#define HID 4096
#define CONCAT 6144
#define OUT_DIM 2048

typedef __attribute__((ext_vector_type(8))) short s8v;
typedef __attribute__((ext_vector_type(4))) float f4v;
typedef __attribute__((ext_vector_type(4))) uint32_t u32x4;

#define SENT 0xFFFFFFFFu    // sentinel; sigmoid output in (0,1) never matches
#define RELAY_SPIN 20000    // relay MALL poll budget (no sleep, ~700cy/iter)
#define FALLBACK_SPIN 100000
#define FLAG_BUDGET 24      // consumer L2 flag polls before falling back to MALL path

// ---------------- ws layout (bytes) ----------------
// Z:      [0, 33554432)          float Z[SEQ][HID]
// hbuf:   [33554432, 67108864)   float hbuf[SEQ][HID] (sentinel-armed; data-as-flag at MALL)
// Xb:     [33554432, +8MB) Wxb: [41943040, +16MB)  bf16 (overlap hbuf; dead before memset)
// flags:  [67108864, +2097152)   u32, per (xcd,t,slice), 16B stride   | only if ws_size
// claim:  [69206016, +4096)      int[8] relay election               | allows (>=69472256)
// hbx:    [69210112, +262144)    float[8][2][4096] per-XCD h staging |

// ---------------- K1: pack bf16 ----------------
__global__ __launch_bounds__(256) void k1_prep(const float* __restrict__ X,
                                               const float* __restrict__ Wi2h,
                                               __hip_bfloat16* __restrict__ Xb,
                                               __hip_bfloat16* __restrict__ Wxb) {
  int gid = blockIdx.x * blockDim.x + threadIdx.x;
  int stride = gridDim.x * blockDim.x;
  for (int i = gid; i < SEQ * IN_DIM; i += stride)
    Xb[i] = __float2bfloat16(X[i]);
  for (int i = gid; i < HID * IN_DIM; i += stride) {
    int r = i >> 11, c = i & (IN_DIM - 1);
    Wxb[i] = __float2bfloat16(Wi2h[(long long)r * CONCAT + c]);
  }
}

// ---------------- K2: Z = Xb @ Wxb^T + b  (bf16 MFMA, 64x64 tiles) ----------------
__global__ __launch_bounds__(256) void k2_zgemm(const __hip_bfloat16* __restrict__ Xb,
                                                const __hip_bfloat16* __restrict__ Wxb,
                                                const float* __restrict__ bias,
                                                float* __restrict__ Z) {
  __shared__ __align__(16) __hip_bfloat16 As[64][40];
  __shared__ __align__(16) __hip_bfloat16 Bs[64][40];
  const int bm = blockIdx.x & 31;
  const int bn = blockIdx.x >> 5;
  const int tid = threadIdx.x;
  const int wv = tid >> 6, l = tid & 63;
  const int wr = (wv >> 1) * 32, wc = (wv & 1) * 32;
  const int fr = l & 15, fko = (l >> 4) * 8;

  f4v acc[2][2] = {};
  const int r = tid >> 2, cc = (tid & 3) * 8;
  const __hip_bfloat16* ga = Xb + (long long)(bm * 64 + r) * IN_DIM + cc;
  const __hip_bfloat16* gb = Wxb + (long long)(bn * 64 + r) * IN_DIM + cc;

  for (int k0 = 0; k0 < IN_DIM; k0 += 32) {
    *(s8v*)&As[r][cc] = *(const s8v*)(ga + k0);
    *(s8v*)&Bs[r][cc] = *(const s8v*)(gb + k0);
    __syncthreads();
    s8v a0 = *(const s8v*)&As[wr + fr][fko];
    s8v a1 = *(const s8v*)&As[wr + 16 + fr][fko];
    s8v b0 = *(const s8v*)&Bs[wc + fr][fko];
    s8v b1 = *(const s8v*)&Bs[wc + 16 + fr][fko];
    acc[0][0] = __builtin_amdgcn_mfma_f32_16x16x32_bf16(a0, b0, acc[0][0], 0, 0, 0);
    acc[0][1] = __builtin_amdgcn_mfma_f32_16x16x32_bf16(a0, b1, acc[0][1], 0, 0, 0);
    acc[1][0] = __builtin_amdgcn_mfma_f32_16x16x32_bf16(a1, b0, acc[1][0], 0, 0, 0);
    acc[1][1] = __builtin_amdgcn_mfma_f32_16x16x32_bf16(a1, b1, acc[1][1], 0, 0, 0);
    __syncthreads();
  }
#pragma unroll
  for (int fm = 0; fm < 2; ++fm)
#pragma unroll
    for (int fn = 0; fn < 2; ++fn)
#pragma unroll
      for (int i = 0; i < 4; ++i) {
        int row = bm * 64 + wr + fm * 16 + (l >> 4) * 4 + i;
        int col = bn * 64 + wc + fn * 16 + fr;
        Z[(long long)row * HID + col] = acc[fm][fn][i] + bias[col];
      }
}

// ---------------- K3: persistent-weight recurrence, per-XCD relay broadcast ----------------
// 256 WGs x 512 thr. WG w owns h rows [16w,16w+16). Wave v owns K-slice [512v,512(v+1)).
// One relay WG per XCD (runtime-claimed via HW_REG_XCC_ID + CAS) polls h[t] at MALL
// (sc1 atomics, proven path), copies into per-XCD hbx via normal stores (write-through
// to local L2), sets per-slice flag. Consumers spin on the flag with sc0 loads
// (L1-bypass, L2-served; same physical L2 => coherent) then sc0-load the data.
// Flag-budget exhaust falls back to the proven MALL sentinel poll => worst case ~R4 perf.
__global__ __launch_bounds__(512, 1) void k3_rnn(const float* __restrict__ Wi2h,
                                                 const float* __restrict__ Z,
                                                 float* __restrict__ hbuf,
                                                 uint32_t* __restrict__ flagsx,
                                                 int* __restrict__ claim,
                                                 float* __restrict__ hbx) {
  const int w = blockIdx.x;
  const int tid = threadIdx.x;
  const int v = tid >> 6;
  const int l = tid & 63;
  const int rowbase = w * 16;
  const bool relay_mode = (hbx != nullptr);

  // ---- relay election (actual XCD id; robust to any block->XCD mapping) ----
  __shared__ int s_xcd, s_rel;
  if (tid == 0) {
    int xr = 0, rl = 0;
    if (relay_mode) {
      uint32_t x;
      asm volatile("s_getreg_b32 %0, hwreg(HW_REG_XCC_ID)" : "=s"(x));
      x &= 7u;
      int old = atomicCAS(&claim[x], -1, w);   // claim[] armed to 0xFF each launch
      xr = (int)x; rl = (old == -1);
    }
    s_xcd = xr; s_rel = rl;
  }
  __syncthreads();
  const int xcd = s_xcd;
  const bool is_relay = (s_rel != 0);

  // ---- weights in registers; lane->k map differs by role ----
  // relay:    k = 512v + 64j + l   (strided: coalesced MALL polls + hbx stores)
  // consumer: k = 512v + 8l + j    (contiguous: 2x dwordx4 sc0 reads from hbx)
  // Both maps cover the wave's 512-wide K-slice exactly once => butterfly row-sums
  // are map-invariant.
  const int koff = is_relay ? (v * 512 + l) : (v * 512 + 8 * l);
  const int kstep = is_relay ? 64 : 1;
  float Wreg[16][8];
#pragma unroll
  for (int r = 0; r < 16; ++r) {
    const float* src = Wi2h + (long long)(rowbase + r) * CONCAT + IN_DIM + koff;
#pragma unroll
    for (int j = 0; j < 8; ++j) Wreg[r][j] = src[kstep * j];
  }
#pragma unroll
  for (int r = 0; r < 16; ++r)
#pragma unroll
    for (int j = 0; j < 8; ++j)
      asm volatile("" : "+v"(Wreg[r][j]));   // pin: no remat/sink into t-loop

  __shared__ float part[2][8][16];
  const int lm = l & 15;
  const int r_mine = ((lm & 1) << 3) | ((lm & 2) << 1) | ((lm & 4) >> 1) | ((lm & 8) >> 3);

  for (int t = 0; t < SEQ - 1; ++t) {
    float zv = 0.f;
    if (v == 0 && l < 16) zv = Z[(long long)t * HID + rowbase + l];

    float hv[8];
#pragma unroll
    for (int j = 0; j < 8; ++j) hv[j] = __builtin_bit_cast(float, SENT);

    if (t > 0) {
      const int slot = xcd * 2 + (t & 1);
      if (is_relay) {
        // --- MALL sentinel poll (proven), strided map, tight (no sleep: 64 waves only) ---
        const uint32_t* hrow = (const uint32_t*)hbuf + (long long)t * HID + v * 512 + l;
        uint32_t u[8];
        bool got[8];
#pragma unroll
        for (int j = 0; j < 8; ++j) got[j] = false;
        int spins = 0;
        while (true) {
          bool allg = true;
#pragma unroll
          for (int j = 0; j < 8; ++j) {
            if (!got[j]) {
              u[j] = __hip_atomic_load(hrow + 64 * j, __ATOMIC_RELAXED, __HIP_MEMORY_SCOPE_AGENT);
              got[j] = (u[j] != SENT);
            }
            allg &= got[j];
          }
          if (__all(allg)) break;
          if (++spins > RELAY_SPIN) break;   // fail loud, not hang
        }
        // --- copy into local-XCD staging (write-through to this XCD's L2) ---
        float* dst = hbx + (long long)slot * 4096 + v * 512 + l;
#pragma unroll
        for (int j = 0; j < 8; ++j) dst[64 * j] = __builtin_bit_cast(float, u[j]);
        asm volatile("s_waitcnt vmcnt(0)" ::: "memory");   // data in L2 before flag
        if (l == 0) flagsx[(((size_t)xcd * 2048 + t) * 8 + v) << 2] = 1u;
#pragma unroll
        for (int j = 0; j < 8; ++j) hv[j] = __builtin_bit_cast(float, u[j]);
      } else {
        bool fast = false;
        if (relay_mode) {
          // --- spin on per-slice flag in local L2 (sc0 = L1-bypass) ---
          const uint32_t* fp = flagsx + ((((size_t)xcd * 2048 + t) * 8 + v) << 2);
          uint32_t f = SENT;
          for (int it = 0; it < FLAG_BUDGET; ++it) {
            asm volatile("global_load_dword %0, %1, off sc0\n\ts_waitcnt vmcnt(0)"
                         : "=&v"(f) : "v"(fp) : "memory");
            if (f != SENT) break;
            __builtin_amdgcn_s_sleep(1);
          }
          if (__all(f != SENT)) {
            const float* src = hbx + (long long)slot * 4096 + v * 512 + 8 * l;
            u32x4 da, db;
            asm volatile("global_load_dwordx4 %0, %2, off sc0\n\t"
                         "global_load_dwordx4 %1, %2, off offset:16 sc0\n\t"
                         "s_waitcnt vmcnt(0)"
                         : "=&v"(da), "=&v"(db) : "v"(src) : "memory");
#pragma unroll
            for (int j = 0; j < 4; ++j) hv[j] = __builtin_bit_cast(float, da[j]);
#pragma unroll
            for (int j = 0; j < 4; ++j) hv[4 + j] = __builtin_bit_cast(float, db[j]);
            fast = true;
          }
        }
        if (!fast) {
          // --- fallback: proven MALL sentinel poll (contiguous map, x4 system-scope) ---
          const uint32_t* hrow = (const uint32_t*)hbuf + (long long)t * HID + v * 512 + 8 * l;
          u32x4 da, db;
#pragma unroll
          for (int j = 0; j < 4; ++j) { da[j] = SENT; db[j] = SENT; }
          bool gota = false, gotb = false;
          int spins = 0;
          while (true) {
            if (!gota) {
              u32x4 ta;
              asm volatile("global_load_dwordx4 %0, %1, off sc0 sc1\n\ts_waitcnt vmcnt(0)"
                           : "=&v"(ta) : "v"(hrow) : "memory");
              if (ta[0] != SENT && ta[1] != SENT && ta[2] != SENT && ta[3] != SENT) { da = ta; gota = true; }
            }
            if (!gotb) {
              u32x4 tb;
              asm volatile("global_load_dwordx4 %0, %1, off offset:16 sc0 sc1\n\ts_waitcnt vmcnt(0)"
                           : "=&v"(tb) : "v"(hrow) : "memory");
              if (tb[0] != SENT && tb[1] != SENT && tb[2] != SENT && tb[3] != SENT) { db = tb; gotb = true; }
            }
            if (__all(gota && gotb)) break;
            if (++spins > FALLBACK_SPIN) break;
            __builtin_amdgcn_s_sleep(1);
          }
#pragma unroll
          for (int j = 0; j < 4; ++j) hv[j] = __builtin_bit_cast(float, da[j]);
#pragma unroll
          for (int j = 0; j < 4; ++j) hv[4 + j] = __builtin_bit_cast(float, db[j]);
        }
      }
    }

    float acc[16];
#pragma unroll
    for (int r = 0; r < 16; ++r) acc[r] = 0.f;
    if (t > 0) {
#pragma unroll
      for (int r = 0; r < 16; ++r)
#pragma unroll
        for (int j = 0; j < 8; ++j)
          acc[r] = fmaf(Wreg[r][j], hv[j], acc[r]);
    }

    // reduce-scatter butterfly: 16 accs across 64 lanes -> 1 row-sum per lane-of-16
#pragma unroll
    for (int i = 0; i < 8; ++i) {
      float send = (l & 1) ? acc[i] : acc[i + 8];
      float keep = (l & 1) ? acc[i + 8] : acc[i];
      acc[i] = keep + __shfl_xor(send, 1, 64);
    }
#pragma unroll
    for (int i = 0; i < 4; ++i) {
      float send = (l & 2) ? acc[i] : acc[i + 4];
      float keep = (l & 2) ? acc[i + 4] : acc[i];
      acc[i] = keep + __shfl_xor(send, 2, 64);
    }
#pragma unroll
    for (int i = 0; i < 2; ++i) {
      float send = (l & 4) ? acc[i] : acc[i + 2];
      float keep = (l & 4) ? acc[i + 2] : acc[i];
      acc[i] = keep + __shfl_xor(send, 4, 64);
    }
    {
      float send = (l & 8) ? acc[0] : acc[1];
      float keep = (l & 8) ? acc[1] : acc[0];
      acc[0] = keep + __shfl_xor(send, 8, 64);
    }
    float rsum = acc[0];
    rsum += __shfl_xor(rsum, 16, 64);
    rsum += __shfl_xor(rsum, 32, 64);

    const int b = t & 1;
    if (l < 16) part[b][v][r_mine] = rsum;
    __syncthreads();

    if (v == 0 && l < 16) {
      float s = 0.f;
#pragma unroll
      for (int q = 0; q < 8; ++q) s += part[b][q][l];
      float pre = s + zv;
      float hn = 1.0f / (1.0f + __expf(-pre));
      // store IS the signal at the MALL
      __hip_atomic_store(hbuf + (long long)(t + 1) * HID + rowbase + l, hn,
                         __ATOMIC_RELAXED, __HIP_MEMORY_SCOPE_AGENT);
    }
  }
}

// ---------------- K4: out = W_i2o @ [x_last, h_last] + b ----------------
__global__ __launch_bounds__(256) void k4_out(const float* __restrict__ X,
                                              const float* __restrict__ Wi2o,
                                              const float* __restrict__ bi2o,
                                              const float* __restrict__ hbuf,
                                              float* __restrict__ out) {
  const int v = threadIdx.x >> 6, l = threadIdx.x & 63;
  const int o = blockIdx.x * 4 + v;
  const float* wrow = Wi2o + (long long)o * CONCAT;
  const float* xlast = X + (long long)(SEQ - 1) * IN_DIM;
  const float* hlast = hbuf + (long long)(SEQ - 1) * HID;
  float s = 0.f;
  for (int k = l; k < IN_DIM; k += 64) s = fmaf(wrow[k], xlast[k], s);
  for (int k = l; k < HID; k += 64) s = fmaf(wrow[IN_DIM + k], hlast[k], s);
#pragma unroll
  for (int m = 1; m < 64; m <<= 1) s += __shfl_xor(s, m, 64);
  if (l == 0) out[o] = s + bi2o[o];
}

extern "C" void kernel_launch(void* const* d_in, const int* in_sizes, int n_in,
                              void* d_out, int out_size, void* d_ws, size_t ws_size,
                              hipStream_t stream) {
  (void)in_sizes; (void)n_in; (void)out_size;
  const float* X    = (const float*)d_in[0];
  const float* Wi2h = (const float*)d_in[1];
  const float* bi2h = (const float*)d_in[2];
  const float* Wi2o = (const float*)d_in[3];
  const float* bi2o = (const float*)d_in[4];
  float* out = (float*)d_out;

  char* ws = (char*)d_ws;
  float* Z            = (float*)(ws);
  float* hbuf         = (float*)(ws + 33554432);
  __hip_bfloat16* Xb  = (__hip_bfloat16*)(ws + 33554432);  // overlaps hbuf (dead before memset)
  __hip_bfloat16* Wxb = (__hip_bfloat16*)(ws + 41943040);

  const bool use_relay = (ws_size >= 69472256ull);
  uint32_t* flagsx = use_relay ? (uint32_t*)(ws + 67108864) : nullptr;
  int* claim       = use_relay ? (int*)(ws + 69206016) : nullptr;
  float* hbx       = use_relay ? (float*)(ws + 69210112) : nullptr;

  hipLaunchKernelGGL(k1_prep, dim3(2048), dim3(256), 0, stream, X, Wi2h, Xb, Wxb);
  hipLaunchKernelGGL(k2_zgemm, dim3(2048), dim3(256), 0, stream, Xb, Wxb, bi2h, Z);

  // arm sentinels + flags + claim every launch (stream-ordered, graph-safe)
  hipMemsetAsync(hbuf, 0xFF, use_relay ? 35655680 : 33554432, stream);

  void* args[] = { (void*)&Wi2h, (void*)&Z, (void*)&hbuf,
                   (void*)&flagsx, (void*)&claim, (void*)&hbx };
  hipLaunchCooperativeKernel((void*)k3_rnn, dim3(256), dim3(512), args, 0, stream);

  hipLaunchKernelGGL(k4_out, dim3(512), dim3(256), 0, stream, X, Wi2o, bi2o, hbuf, out);
}

// Round 8
// 5617.300 us; speedup vs baseline: 1.4745x; 1.4745x over previous
//
#include <hip/hip_runtime.h>
#include <hip/hip_bf16.h>
#include <stdint.h>

#define SEQ 2048
#define IN_DIM 2048
#define HID 4096
#define CONCAT 6144
#define OUT_DIM 2048

typedef __attribute__((ext_vector_type(8))) short s8v;
typedef __attribute__((ext_vector_type(4))) float f4v;

#define SENT 0xFFFFFFFFu   // sentinel; sigmoid output in (0,1) never matches
#define SPIN_BUDGET 20000  // ~14 ms/step worst case: fail loud (absmax), not hang

// ---------------- ws layout (bytes) ----------------
// Z:     [0, 33554432)            float Z[SEQ][HID]
// hbuf:  [33554432, 67108864)     float hbuf[SEQ][HID]   (rows 1..2047 used)
// Xb:    [33554432, +8388608)     bf16  (overlaps hbuf; dead before memset re-arms sentinel)
// Wxb:   [41943040, +16777216)    bf16
// total required: 67,108,864 B

// ---------------- K1: pack bf16 ----------------
__global__ __launch_bounds__(256) void k1_prep(const float* __restrict__ X,
                                               const float* __restrict__ Wi2h,
                                               __hip_bfloat16* __restrict__ Xb,
                                               __hip_bfloat16* __restrict__ Wxb) {
  int gid = blockIdx.x * blockDim.x + threadIdx.x;
  int stride = gridDim.x * blockDim.x;
  for (int i = gid; i < SEQ * IN_DIM; i += stride)
    Xb[i] = __float2bfloat16(X[i]);
  for (int i = gid; i < HID * IN_DIM; i += stride) {
    int r = i >> 11, c = i & (IN_DIM - 1);
    Wxb[i] = __float2bfloat16(Wi2h[(long long)r * CONCAT + c]);
  }
}

// ---------------- K2: Z = Xb @ Wxb^T + b  (bf16 MFMA, 64x64 tiles) ----------------
__global__ __launch_bounds__(256) void k2_zgemm(const __hip_bfloat16* __restrict__ Xb,
                                                const __hip_bfloat16* __restrict__ Wxb,
                                                const float* __restrict__ bias,
                                                float* __restrict__ Z) {
  __shared__ __align__(16) __hip_bfloat16 As[64][40];  // +8 pad: kills ds_read conflicts
  __shared__ __align__(16) __hip_bfloat16 Bs[64][40];
  const int bm = blockIdx.x & 31;   // 32 M-tiles (SEQ/64)
  const int bn = blockIdx.x >> 5;   // 64 N-tiles (HID/64)
  const int tid = threadIdx.x;
  const int wv = tid >> 6, l = tid & 63;
  const int wr = (wv >> 1) * 32, wc = (wv & 1) * 32;   // wave's 32x32 quadrant
  const int fr = l & 15, fko = (l >> 4) * 8;

  f4v acc[2][2] = {};
  const int r = tid >> 2, cc = (tid & 3) * 8;          // staging: row, 8-elem chunk
  const __hip_bfloat16* ga = Xb + (long long)(bm * 64 + r) * IN_DIM + cc;
  const __hip_bfloat16* gb = Wxb + (long long)(bn * 64 + r) * IN_DIM + cc;

  for (int k0 = 0; k0 < IN_DIM; k0 += 32) {
    *(s8v*)&As[r][cc] = *(const s8v*)(ga + k0);
    *(s8v*)&Bs[r][cc] = *(const s8v*)(gb + k0);
    __syncthreads();
    s8v a0 = *(const s8v*)&As[wr + fr][fko];
    s8v a1 = *(const s8v*)&As[wr + 16 + fr][fko];
    s8v b0 = *(const s8v*)&Bs[wc + fr][fko];
    s8v b1 = *(const s8v*)&Bs[wc + 16 + fr][fko];
    acc[0][0] = __builtin_amdgcn_mfma_f32_16x16x32_bf16(a0, b0, acc[0][0], 0, 0, 0);
    acc[0][1] = __builtin_amdgcn_mfma_f32_16x16x32_bf16(a0, b1, acc[0][1], 0, 0, 0);
    acc[1][0] = __builtin_amdgcn_mfma_f32_16x16x32_bf16(a1, b0, acc[1][0], 0, 0, 0);
    acc[1][1] = __builtin_amdgcn_mfma_f32_16x16x32_bf16(a1, b1, acc[1][1], 0, 0, 0);
    __syncthreads();
  }
#pragma unroll
  for (int fm = 0; fm < 2; ++fm)
#pragma unroll
    for (int fn = 0; fn < 2; ++fn)
#pragma unroll
      for (int i = 0; i < 4; ++i) {
        int row = bm * 64 + wr + fm * 16 + (l >> 4) * 4 + i;
        int col = bn * 64 + wc + fn * 16 + fr;
        Z[(long long)row * HID + col] = acc[fm][fn][i] + bias[col];
      }
}

// ---------------- K3: persistent-weight recurrence (cooperative) ----------------
// 256 WGs x 512 thr. WG w owns h rows [16w,16w+16). Wave v owns K-slice [512v,512(v+1)).
// Lane l: k = 512v + 64j + l (j=0..7); weights Wreg[16][8] pinned (AGPR-resident).
// Sync: DATA-AS-FLAG at the MALL (relaxed agent atomics, sc1). R7 proved poll pressure
// at the coherence point is NOT the limiter (per-XCD relay = null), so consumers spin
// TIGHT (no s_sleep: lower detect quantization + keeps clocks up). INCREMENTAL FMA:
// poll-group j depends on only 4 producer WGs; as soon as __all(got[j]) the group's
// 16 FMAs run (wave-uniform), overlapping later groups' detection.
__global__ __launch_bounds__(512, 1) void k3_rnn(const float* __restrict__ Wi2h,
                                                 const float* __restrict__ Z,
                                                 float* __restrict__ hbuf) {
  const int w = blockIdx.x;
  const int tid = threadIdx.x;
  const int v = tid >> 6;
  const int l = tid & 63;
  const int rowbase = w * 16;
  const int kbase = v * 512 + l;

  float Wreg[16][8];
#pragma unroll
  for (int r = 0; r < 16; ++r) {
    const float* src = Wi2h + (long long)(rowbase + r) * CONCAT + IN_DIM + kbase;
#pragma unroll
    for (int j = 0; j < 8; ++j) Wreg[r][j] = src[64 * j];
  }
  // pin weights: opaque identity so the compiler can neither rematerialize from
  // memory nor sink the loads into the t-loop
#pragma unroll
  for (int r = 0; r < 16; ++r)
#pragma unroll
    for (int j = 0; j < 8; ++j)
      asm volatile("" : "+v"(Wreg[r][j]));

  __shared__ float part[2][8][16];
  const int lm = l & 15;
  const int r_mine = ((lm & 1) << 3) | ((lm & 2) << 1) | ((lm & 4) >> 1) | ((lm & 8) >> 3);

  for (int t = 0; t < SEQ - 1; ++t) {
    // prefetch z for this WG's rows (independent of h)
    float zv = 0.f;
    if (v == 0 && l < 16) zv = Z[(long long)t * HID + rowbase + l];

    float acc[16];
#pragma unroll
    for (int r = 0; r < 16; ++r) acc[r] = 0.f;

    if (t > 0) {
      // data-as-flag poll with incremental per-group FMA. Group j (one dword/lane,
      // rows 512v+64j .. +63) is produced by just 4 WGs -> completes early and its
      // FMAs overlap detection of the remaining groups.
      const uint32_t* hrow = (const uint32_t*)hbuf + (long long)t * HID + kbase;
      bool done[8];
#pragma unroll
      for (int j = 0; j < 8; ++j) done[j] = false;
      int spins = 0;
      while (true) {
        uint32_t uj[8];
#pragma unroll
        for (int j = 0; j < 8; ++j)
          if (!done[j])
            uj[j] = __hip_atomic_load(hrow + 64 * j, __ATOMIC_RELAXED, __HIP_MEMORY_SCOPE_AGENT);
        bool alldone = true;
#pragma unroll
        for (int j = 0; j < 8; ++j) {
          if (!done[j]) {
            if (__all(uj[j] != SENT)) {   // wave-uniform trigger
              float h = __builtin_bit_cast(float, uj[j]);
#pragma unroll
              for (int r = 0; r < 16; ++r)
                acc[r] = fmaf(Wreg[r][j], h, acc[r]);
              done[j] = true;
            } else {
              alldone = false;
            }
          }
        }
        if (alldone) break;
        if (++spins > SPIN_BUDGET) break;  // deadlock insurance: fail loud, not hang
      }
    }

    // reduce-scatter butterfly: 16 accs across 64 lanes -> 1 row-sum per lane-of-16
#pragma unroll
    for (int i = 0; i < 8; ++i) {
      float send = (l & 1) ? acc[i] : acc[i + 8];
      float keep = (l & 1) ? acc[i + 8] : acc[i];
      acc[i] = keep + __shfl_xor(send, 1, 64);
    }
#pragma unroll
    for (int i = 0; i < 4; ++i) {
      float send = (l & 2) ? acc[i] : acc[i + 4];
      float keep = (l & 2) ? acc[i + 4] : acc[i];
      acc[i] = keep + __shfl_xor(send, 2, 64);
    }
#pragma unroll
    for (int i = 0; i < 2; ++i) {
      float send = (l & 4) ? acc[i] : acc[i + 2];
      float keep = (l & 4) ? acc[i + 2] : acc[i];
      acc[i] = keep + __shfl_xor(send, 4, 64);
    }
    {
      float send = (l & 8) ? acc[0] : acc[1];
      float keep = (l & 8) ? acc[1] : acc[0];
      acc[0] = keep + __shfl_xor(send, 8, 64);
    }
    float rsum = acc[0];
    rsum += __shfl_xor(rsum, 16, 64);
    rsum += __shfl_xor(rsum, 32, 64);

    const int b = t & 1;
    if (l < 16) part[b][v][r_mine] = rsum;
    __syncthreads();

    if (v == 0 && l < 16) {
      float s = 0.f;
#pragma unroll
      for (int q = 0; q < 8; ++q) s += part[b][q][l];
      float pre = s + zv;
      float hn = 1.0f / (1.0f + __expf(-pre));
      // store IS the signal — no ordering wait needed
      __hip_atomic_store(hbuf + (long long)(t + 1) * HID + rowbase + l, hn,
                         __ATOMIC_RELAXED, __HIP_MEMORY_SCOPE_AGENT);
    }
    // no second __syncthreads: LDS 'part' is double-buffered; waves pipeline into
    // the next step's poll while wave 0 finalizes.
  }
}

// ---------------- K4: out = W_i2o @ [x_last, h_last] + b ----------------
__global__ __launch_bounds__(256) void k4_out(const float* __restrict__ X,
                                              const float* __restrict__ Wi2o,
                                              const float* __restrict__ bi2o,
                                              const float* __restrict__ hbuf,
                                              float* __restrict__ out) {
  const int v = threadIdx.x >> 6, l = threadIdx.x & 63;
  const int o = blockIdx.x * 4 + v;
  const float* wrow = Wi2o + (long long)o * CONCAT;
  const float* xlast = X + (long long)(SEQ - 1) * IN_DIM;
  const float* hlast = hbuf + (long long)(SEQ - 1) * HID;
  float s = 0.f;
  for (int k = l; k < IN_DIM; k += 64) s = fmaf(wrow[k], xlast[k], s);
  for (int k = l; k < HID; k += 64) s = fmaf(wrow[IN_DIM + k], hlast[k], s);
#pragma unroll
  for (int m = 1; m < 64; m <<= 1) s += __shfl_xor(s, m, 64);
  if (l == 0) out[o] = s + bi2o[o];
}

extern "C" void kernel_launch(void* const* d_in, const int* in_sizes, int n_in,
                              void* d_out, int out_size, void* d_ws, size_t ws_size,
                              hipStream_t stream) {
  (void)in_sizes; (void)n_in; (void)out_size; (void)ws_size;
  const float* X    = (const float*)d_in[0];
  const float* Wi2h = (const float*)d_in[1];
  const float* bi2h = (const float*)d_in[2];
  const float* Wi2o = (const float*)d_in[3];
  const float* bi2o = (const float*)d_in[4];
  float* out = (float*)d_out;

  char* ws = (char*)d_ws;
  float* Z            = (float*)(ws);
  float* hbuf         = (float*)(ws + 33554432);
  __hip_bfloat16* Xb  = (__hip_bfloat16*)(ws + 33554432);  // overlaps hbuf (dead before memset)
  __hip_bfloat16* Wxb = (__hip_bfloat16*)(ws + 41943040);

  hipLaunchKernelGGL(k1_prep, dim3(2048), dim3(256), 0, stream, X, Wi2h, Xb, Wxb);
  hipLaunchKernelGGL(k2_zgemm, dim3(2048), dim3(256), 0, stream, Xb, Wxb, bi2h, Z);

  // re-arm the data-as-flag sentinel every launch (graph-capture safe, stream-ordered)
  hipMemsetAsync(hbuf, 0xFF, 33554432, stream);

  void* args[] = { (void*)&Wi2h, (void*)&Z, (void*)&hbuf };
  hipLaunchCooperativeKernel((void*)k3_rnn, dim3(256), dim3(512), args, 0, stream);

  hipLaunchKernelGGL(k4_out, dim3(512), dim3(256), 0, stream, X, Wi2o, bi2o, hbuf, out);
}